// Round 1
// 337.755 us; speedup vs baseline: 1.0429x; 1.0429x over previous
//
#include <hip/hip_runtime.h>

// Problem constants (MultiScaleRetention: B=4, L=4096, D=1024, H=16, DH=64)
#define BB 4
#define LL 4096
#define DM 1024
#define NH 16
#define MM (BB * LL)   // 16384 rows
#define CC2 256        // scan chunks per sequence
#define LC2 16         // chunk length (CC2*LC2 == LL)

// GEMM geometry: 256x256 tile, BK=64, 8 waves (2Mx4N), 8-phase schedule
#define BKT 64
#define NKT (DM / BKT)   // 16 K-tiles (power of 2 -> wrap mask)

typedef unsigned short u16;
typedef float f32x4 __attribute__((ext_vector_type(4)));
typedef __bf16 mfma_in __attribute__((ext_vector_type(8)));

__device__ __forceinline__ u16 f2bf(float f) {
    unsigned u = __float_as_uint(f);
    u += 0x7FFFu + ((u >> 16) & 1u);   // RNE
    return (u16)(u >> 16);
}
__device__ __forceinline__ float bf2f(u16 u) {
    return __uint_as_float(((unsigned)u) << 16);
}

// async global->LDS, 16B per lane; LDS dest = wave-uniform base + lane*16
__device__ __forceinline__ void gld_lds16(const u16* g, u16* l) {
    __builtin_amdgcn_global_load_lds(
        (const __attribute__((address_space(1))) void*)g,
        (__attribute__((address_space(3))) void*)l,
        16, 0, 0);
}

// ---------------------------------------------------------------- conversions
#define XF4 (MM * DM / 4)
#define WF4 (DM * DM / 4)
__global__ __launch_bounds__(256)
void cvt_all(const float* __restrict__ x,
             const float* __restrict__ w0, const float* __restrict__ w1,
             const float* __restrict__ w2, const float* __restrict__ w3,
             u16* __restrict__ dst) {
    int i = blockIdx.x * 256 + threadIdx.x;
    const float* src;
    int si;
    if (i < XF4) { src = x; si = i; }
    else {
        int j = i - XF4;
        const float* ws[4] = {w0, w1, w2, w3};
        src = ws[j >> 18];
        si = j & (WF4 - 1);
    }
    float4 f = ((const float4*)src)[si];
    ushort4 o;
    o.x = f2bf(f.x); o.y = f2bf(f.y); o.z = f2bf(f.z); o.w = f2bf(f.w);
    ((ushort4*)dst)[i] = o;
}

// ---------------------------------------------------------------- 256^2 8-phase GEMM
// LDS layout per 256x64 K-tile buffer: row = 64 u16 (8 chunks of 16B),
// chunk at (row, logical c) stored at phys = c ^ (row&7) (XOR bank swizzle).
// Staging (per global_load_lds, all 8 waves): wave w lane l covers
//   row  = segBase + w*8 + (l>>3), phys chunk l&7
//   -> logical chunk (l&7)^(l>>3) pre-swizzled into the GLOBAL source address.
// Fragment read: row r, k-step s, logical chunk 4s+quad -> phys (4s+quad)^(r&7).
//
// 8-phase schedule per iteration (2 K-tiles k=2it -> buf0, k+1 -> buf1):
//   ph1 Q0(i0-3,j0-1)@buf0: ld aL,bL | stage B-h0(k+1)->buf1
//   ph2 Q1(i4-7,j0-1)@buf0: ld aH    | stage B-h1(k+1)->buf1
//   ph3 Q2(i0-3,j2-3)@buf0: ld bH    | stage A-h0(k+2)->buf0   (A slots last read ph2)
//   ph4 Q3(i4-7,j2-3)@buf0:          | stage A-h1(k+2)->buf0 | vmcnt(4)
//   ph5..ph8: same on buf1; stages B(k+2)->buf0, A(k+3)->buf1 | vmcnt(4)
// vmcnt(4) leaves only the 2 newest half-tiles (A of tile+2/+3) in flight;
// everything the next tile's reads need has landed. Stage K-index wraps &15 at
// the tail: garbage lands only in slots whose last read already happened.

template<int IOFF, int JOFF>
__device__ __forceinline__ void mfmaQ(const mfma_in (&a)[4][2], const mfma_in (&b)[2][2],
                                      f32x4 (&acc)[8][4]) {
#pragma unroll
    for (int s = 0; s < 2; s++)
#pragma unroll
        for (int i = 0; i < 4; i++)
#pragma unroll
            for (int j = 0; j < 2; j++)
                acc[IOFF + i][JOFF + j] = __builtin_amdgcn_mfma_f32_16x16x32_bf16(
                    a[i][s], b[j][s], acc[IOFF + i][JOFF + j], 0, 0, 0);
}

#define PH_MID() do { \
    __builtin_amdgcn_s_barrier(); \
    asm volatile("s_waitcnt lgkmcnt(0)" ::: "memory"); \
    __builtin_amdgcn_sched_barrier(0); \
    __builtin_amdgcn_s_setprio(1); \
} while (0)

#define PH_END() do { \
    __builtin_amdgcn_s_setprio(0); \
    __builtin_amdgcn_sched_barrier(0); \
    __builtin_amdgcn_s_barrier(); \
} while (0)

#define PH_END_VM() do { \
    __builtin_amdgcn_s_setprio(0); \
    __builtin_amdgcn_sched_barrier(0); \
    asm volatile("s_waitcnt vmcnt(4)" ::: "memory"); \
    __builtin_amdgcn_s_barrier(); \
} while (0)

__device__ __forceinline__ void mainloop256(
    const u16* __restrict__ A, const u16* __restrict__ B,
    int mBlk, int nBlk,
    u16 (*__restrict__ As)[256 * 64], u16 (*__restrict__ Bs)[256 * 64],
    f32x4 (&acc)[8][4]) {
    const int tid  = threadIdx.x;
    const int wave = tid >> 6;
    const int lane = tid & 63;
    const int quad = lane >> 4;
    const int l16  = lane & 15;
    const int wm   = (wave >> 2) * 128;   // wave-row: 0..1 -> A half
    const int wn   = (wave & 3) * 64;     // wave-col: 0..3

    // staging addressing (swizzle folded into global source)
    const int sRow = wave * 8 + (lane >> 3);
    const int sCol = ((lane & 7) ^ (lane >> 3)) * 8;
    const u16* gA = A + (size_t)(mBlk + sRow) * DM + sCol;
    const u16* gB = B + (size_t)(nBlk + sRow) * DM + sCol;
    const int ldsW = wave * 8 * 64;       // wave's element offset within a 64-row segment

    // fragment read offsets
    int rA[8], rB[4];
#pragma unroll
    for (int i = 0; i < 8; i++) rA[i] = (wm + i * 16 + l16) * 64;
#pragma unroll
    for (int j = 0; j < 4; j++) rB[j] = (wn + j * 16 + l16) * 64;
    const int c0 = ((quad    ) ^ (l16 & 7)) * 8;
    const int c1 = ((quad + 4) ^ (l16 & 7)) * 8;

#define STG_A(buf, h, t) do { \
    const int kk_ = ((t) & (NKT - 1)) * BKT; \
    gld_lds16(gA + (size_t)((h) * 128) * DM + kk_,      &As[buf][((h) * 128) * 64 + ldsW]); \
    gld_lds16(gA + (size_t)((h) * 128 + 64) * DM + kk_, &As[buf][((h) * 128 + 64) * 64 + ldsW]); \
} while (0)
#define STG_B(buf, h, t) do { \
    const int kk_ = ((t) & (NKT - 1)) * BKT; \
    gld_lds16(gB + (size_t)((h) * 128) * DM + kk_,      &Bs[buf][((h) * 128) * 64 + ldsW]); \
    gld_lds16(gB + (size_t)((h) * 128 + 64) * DM + kk_, &Bs[buf][((h) * 128 + 64) * 64 + ldsW]); \
} while (0)
#define LDA(dst, buf, i, s) (dst) = *(const mfma_in*)&As[buf][rA[i] + ((s) ? c1 : c0)]
#define LDB(dst, buf, j, s) (dst) = *(const mfma_in*)&Bs[buf][rB[j] + ((s) ? c1 : c0)]

    mfma_in aL[4][2], aH[4][2], bL[2][2], bH[2][2];

    // prologue: tile 0 complete + A halves of tile 1 (B(1) staged in ph1/ph2)
    STG_A(0, 0, 0); STG_A(0, 1, 0);
    STG_B(0, 0, 0); STG_B(0, 1, 0);
    STG_A(1, 0, 1); STG_A(1, 1, 1);
    asm volatile("s_waitcnt vmcnt(4)" ::: "memory");   // tile 0's 8 loads landed
    __builtin_amdgcn_s_barrier();

#pragma unroll 1
    for (int it = 0; it < NKT / 2; ++it) {
        const int k = 2 * it;

        // ---- tile k (buf0) ----
        // ph1: Q0
#pragma unroll
        for (int i = 0; i < 4; i++) { LDA(aL[i][0], 0, i, 0); LDA(aL[i][1], 0, i, 1); }
#pragma unroll
        for (int j = 0; j < 2; j++) { LDB(bL[j][0], 0, j, 0); LDB(bL[j][1], 0, j, 1); }
        STG_B(1, 0, k + 1);
        PH_MID();
        mfmaQ<0, 0>(aL, bL, acc);
        PH_END();

        // ph2: Q1
#pragma unroll
        for (int i = 0; i < 4; i++) { LDA(aH[i][0], 0, i + 4, 0); LDA(aH[i][1], 0, i + 4, 1); }
        STG_B(1, 1, k + 1);
        PH_MID();
        mfmaQ<4, 0>(aH, bL, acc);
        PH_END();

        // ph3: Q2
#pragma unroll
        for (int j = 0; j < 2; j++) { LDB(bH[j][0], 0, j + 2, 0); LDB(bH[j][1], 0, j + 2, 1); }
        STG_A(0, 0, k + 2);
        PH_MID();
        mfmaQ<0, 2>(aL, bH, acc);
        PH_END();

        // ph4: Q3
        STG_A(0, 1, k + 2);
        PH_MID();
        mfmaQ<4, 2>(aH, bH, acc);
        PH_END_VM();   // vmcnt(4): only A(k+2) halves in flight; tile k+1 landed

        // ---- tile k+1 (buf1) ----
        // ph5: Q0
#pragma unroll
        for (int i = 0; i < 4; i++) { LDA(aL[i][0], 1, i, 0); LDA(aL[i][1], 1, i, 1); }
#pragma unroll
        for (int j = 0; j < 2; j++) { LDB(bL[j][0], 1, j, 0); LDB(bL[j][1], 1, j, 1); }
        STG_B(0, 0, k + 2);
        PH_MID();
        mfmaQ<0, 0>(aL, bL, acc);
        PH_END();

        // ph6: Q1
#pragma unroll
        for (int i = 0; i < 4; i++) { LDA(aH[i][0], 1, i + 4, 0); LDA(aH[i][1], 1, i + 4, 1); }
        STG_B(0, 1, k + 2);
        PH_MID();
        mfmaQ<4, 0>(aH, bL, acc);
        PH_END();

        // ph7: Q2
#pragma unroll
        for (int j = 0; j < 2; j++) { LDB(bH[j][0], 1, j + 2, 0); LDB(bH[j][1], 1, j + 2, 1); }
        STG_A(1, 0, k + 3);
        PH_MID();
        mfmaQ<0, 2>(aL, bH, acc);
        PH_END();

        // ph8: Q3
        STG_A(1, 1, k + 3);
        PH_MID();
        mfmaQ<4, 2>(aH, bH, acc);
        PH_END_VM();   // vmcnt(4): only A(k+3) halves in flight; tile k+2 landed
    }
#undef STG_A
#undef STG_B
#undef LDA
#undef LDB
}

// fused q/v/g projection: B = concatenated 3072x1024 weights; 3 bf16 outputs
__global__ __launch_bounds__(512, 2)
void gemm_qvg(const u16* __restrict__ A, const u16* __restrict__ B,
              u16* __restrict__ oq, u16* __restrict__ ov, u16* __restrict__ og) {
    __shared__ __align__(16) u16 As[2][256 * 64];
    __shared__ __align__(16) u16 Bs[2][256 * 64];
    const int mBlk = blockIdx.x * 256;
    const int nBlk = blockIdx.y * 256;

    f32x4 acc[8][4] = {};
    mainloop256(A, B, mBlk, nBlk, As, Bs, acc);

    const int tid  = threadIdx.x;
    const int wave = tid >> 6;
    const int lane = tid & 63;
    const int quad = lane >> 4;
    const int l16  = lane & 15;
    const int wm   = (wave >> 2) * 128;
    const int wn   = (wave & 3) * 64;

    u16* outs[3] = {oq, ov, og};
    u16* O = outs[nBlk >> 10];
    const int nIn = nBlk & 1023;
#pragma unroll
    for (int i = 0; i < 8; i++) {
        int row0 = mBlk + wm + i * 16 + quad * 4;
#pragma unroll
        for (int j = 0; j < 4; j++) {
            int col = nIn + wn + j * 16 + l16;
#pragma unroll
            for (int r = 0; r < 4; r++)
                O[(size_t)(row0 + r) * DM + col] = f2bf(acc[i][j][r]);
        }
    }
}

// output projection: C (f32) = A @ B^T
__global__ __launch_bounds__(512, 2)
void gemm_out(const u16* __restrict__ A, const u16* __restrict__ B,
              float* __restrict__ C) {
    __shared__ __align__(16) u16 As[2][256 * 64];
    __shared__ __align__(16) u16 Bs[2][256 * 64];
    const int mBlk = blockIdx.x * 256;
    const int nBlk = blockIdx.y * 256;

    f32x4 acc[8][4] = {};
    mainloop256(A, B, mBlk, nBlk, As, Bs, acc);

    const int tid  = threadIdx.x;
    const int wave = tid >> 6;
    const int lane = tid & 63;
    const int quad = lane >> 4;
    const int l16  = lane & 15;
    const int wm   = (wave >> 2) * 128;
    const int wn   = (wave & 3) * 64;

#pragma unroll
    for (int i = 0; i < 8; i++) {
        int row0 = mBlk + wm + i * 16 + quad * 4;
#pragma unroll
        for (int j = 0; j < 4; j++) {
            int col = nBlk + wn + j * 16 + l16;
#pragma unroll
            for (int r = 0; r < 4; r++)
                C[(size_t)(row0 + r) * DM + col] = acc[i][j][r];
        }
    }
}

// ---------------------------------------------------------------- scan phase A
__global__ __launch_bounds__(256)
void scan_ends(const u16* __restrict__ v, const float* __restrict__ beta,
               float* __restrict__ ebuf) {
    int d = blockIdx.x * 256 + threadIdx.x;
    int c = blockIdx.y, b = blockIdx.z;
    int h = d >> 6;
    float lam = 1.0f / (1.0f + __expf(-beta[h]));
    size_t idx = ((size_t)b * LL + (size_t)c * LC2) * DM + d;
    float s = 0.0f;
#pragma unroll
    for (int i = 0; i < LC2; i++) {
        s = lam * s + bf2f(v[idx]);
        idx += DM;
    }
    ebuf[((size_t)b * CC2 + c) * DM + d] = s;
}

// ---------------------------------------------------------------- scan phase B
__global__ __launch_bounds__(256)
void scan_carry(const float* __restrict__ ebuf, const float* __restrict__ beta,
                float* __restrict__ carry) {
    int ch = blockIdx.x * 256 + threadIdx.x;  // 0..BB*DM-1
    int b = ch >> 10, d = ch & 1023;
    int h = d >> 6;
    float lam = 1.0f / (1.0f + __expf(-beta[h]));
    float lamC = lam;
    for (int i = 0; i < 4; i++) lamC *= lamC;  // lam^16
    float cur = 0.0f;
#pragma unroll 8
    for (int c = 0; c < CC2; c++) {
        size_t idx = ((size_t)b * CC2 + c) * DM + d;
        carry[idx] = cur;
        cur = lamC * cur + ebuf[idx];
    }
}

// ---------------------------------------------------------------- scan phase C:
// seeded re-scan + y=q*state + LayerNorm + SiLU gate -> bf16
__global__ __launch_bounds__(256)
void scan_ln_gate(const u16* __restrict__ v, const u16* __restrict__ q,
                  const u16* __restrict__ g, const float* __restrict__ carry,
                  const float* __restrict__ beta, const float* __restrict__ gamma,
                  const float* __restrict__ lnb, u16* __restrict__ out) {
    __shared__ float red[2][8];
    const int t = threadIdx.x;
    const int c = blockIdx.x, b = blockIdx.y;
    const int wave = t >> 6, lane = t & 63;
    const int d0 = t * 4;
    const int h = d0 >> 6;
    float lam = 1.0f / (1.0f + __expf(-beta[h]));
    float4 gm = ((const float4*)gamma)[t];
    float4 bt = ((const float4*)lnb)[t];
    float4 cr = *(const float4*)(carry + ((size_t)b * CC2 + c) * DM + d0);
    float s0 = cr.x, s1 = cr.y, s2 = cr.z, s3 = cr.w;
    size_t base = ((size_t)b * LL + (size_t)c * LC2) * DM + d0;

    for (int i = 0; i < LC2; i++) {
        ushort4 v4 = *(const ushort4*)(v + base);
        ushort4 q4 = *(const ushort4*)(q + base);
        ushort4 g4 = *(const ushort4*)(g + base);
        s0 = lam * s0 + bf2f(v4.x);
        s1 = lam * s1 + bf2f(v4.y);
        s2 = lam * s2 + bf2f(v4.z);
        s3 = lam * s3 + bf2f(v4.w);
        float y0 = bf2f(q4.x) * s0, y1 = bf2f(q4.y) * s1;
        float y2 = bf2f(q4.z) * s2, y3 = bf2f(q4.w) * s3;
        float sum = y0 + y1 + y2 + y3;
        float sq  = y0 * y0 + y1 * y1 + y2 * y2 + y3 * y3;
#pragma unroll
        for (int off = 32; off > 0; off >>= 1) {
            sum += __shfl_xor(sum, off);
            sq  += __shfl_xor(sq, off);
        }
        int p = i & 1;
        if (lane == 0) { red[p][wave] = sum; red[p][4 + wave] = sq; }
        __syncthreads();
        float ts = red[p][0] + red[p][1] + red[p][2] + red[p][3];
        float tq = red[p][4] + red[p][5] + red[p][6] + red[p][7];
        float mu  = ts * (1.0f / DM);
        float inv = rsqrtf(tq * (1.0f / DM) - mu * mu + 1e-5f);

        float gv0 = bf2f(g4.x), gv1 = bf2f(g4.y), gv2 = bf2f(g4.z), gv3 = bf2f(g4.w);
        float x0 = ((y0 - mu) * inv * gm.x + bt.x) * (gv0 / (1.0f + __expf(-gv0)));
        float x1 = ((y1 - mu) * inv * gm.y + bt.y) * (gv1 / (1.0f + __expf(-gv1)));
        float x2 = ((y2 - mu) * inv * gm.z + bt.z) * (gv2 / (1.0f + __expf(-gv2)));
        float x3 = ((y3 - mu) * inv * gm.w + bt.w) * (gv3 / (1.0f + __expf(-gv3)));
        ushort4 o;
        o.x = f2bf(x0); o.y = f2bf(x1); o.z = f2bf(x2); o.w = f2bf(x3);
        *(ushort4*)(out + base) = o;
        base += DM;
    }
}

// ---------------------------------------------------------------- launcher
extern "C" void kernel_launch(void* const* d_in, const int* in_sizes, int n_in,
                              void* d_out, int out_size, void* d_ws, size_t ws_size,
                              hipStream_t stream) {
    const float* x     = (const float*)d_in[0];
    const float* Wq    = (const float*)d_in[1];
    const float* Wv    = (const float*)d_in[2];
    const float* Wg    = (const float*)d_in[3];
    const float* Wo    = (const float*)d_in[4];
    const float* beta  = (const float*)d_in[5];
    const float* gamma = (const float*)d_in[6];
    const float* lnb   = (const float*)d_in[7];

    // workspace layout (bf16 elements) — xb..Wob contiguous for cvt_all
    u16* xb  = (u16*)d_ws;                    // reused as y_final
    u16* Wqb = xb + (size_t)MM * DM;          // Wq,Wv,Wg concat = 3072x1024
    u16* Wob = Wqb + (size_t)3 * DM * DM;
    u16* qb  = Wob + (size_t)DM * DM;
    u16* vb  = qb + (size_t)MM * DM;
    u16* gb  = vb + (size_t)MM * DM;
    float* ebuf  = (float*)(gb + (size_t)MM * DM);   // BB*CC2*DM f32
    float* carry = ebuf + (size_t)BB * CC2 * DM;
    u16* yfin = xb;

    // 1) fp32 -> bf16, single launch
    cvt_all<<<(XF4 + 4 * WF4 + 255) / 256, 256, 0, stream>>>(x, Wq, Wv, Wg, Wo, xb);

    // 2) fused q/v/g projection (N=3072 concat), 256x256 8-phase
    dim3 gq(MM / 256, 3 * DM / 256);
    gemm_qvg<<<gq, 512, 0, stream>>>(xb, Wqb, qb, vb, gb);

    // 3) retention scan (chunked) + fused LN + SiLU gate
    dim3 gs(DM / 256, CC2, BB);
    scan_ends<<<gs, 256, 0, stream>>>(vb, beta, ebuf);
    scan_carry<<<(BB * DM) / 256, 256, 0, stream>>>(ebuf, beta, carry);
    dim3 gf(CC2, BB);
    scan_ln_gate<<<gf, 256, 0, stream>>>(vb, qb, gb, carry, beta, gamma, lnb, yfin);

    // 4) output projection (fp32 out), 256x256 8-phase
    dim3 go(MM / 256, DM / 256);
    gemm_out<<<go, 512, 0, stream>>>(yfin, Wob, (float*)d_out);
}

// Round 2
// 316.267 us; speedup vs baseline: 1.1138x; 1.0679x over previous
//
#include <hip/hip_runtime.h>

// Problem constants (MultiScaleRetention: B=4, L=4096, D=1024, H=16, DH=64)
#define BB 4
#define LL 4096
#define DM 1024
#define NH 16
#define MM (BB * LL)   // 16384 rows
#define CC2 256        // scan chunks per sequence
#define LC2 16         // chunk length (CC2*LC2 == LL)

// GEMM geometry: 256x256 tile, BK=64, 8 waves (2Mx4N), 8-phase schedule
#define BKT 64
#define NKT (DM / BKT)   // 16 K-tiles (power of 2 -> wrap mask)

typedef unsigned short u16;
typedef float f32x4 __attribute__((ext_vector_type(4)));
typedef int i32x4 __attribute__((ext_vector_type(4)));
typedef __bf16 mfma_in __attribute__((ext_vector_type(8)));

__device__ __forceinline__ u16 f2bf(float f) {
    unsigned u = __float_as_uint(f);
    u += 0x7FFFu + ((u >> 16) & 1u);   // RNE
    return (u16)(u >> 16);
}
__device__ __forceinline__ float bf2f(u16 u) {
    return __uint_as_float(((unsigned)u) << 16);
}

// async global->LDS, 16B per lane; LDS dest = wave-uniform base + lane*16
__device__ __forceinline__ void gld_lds16(const u16* g, u16* l) {
    __builtin_amdgcn_global_load_lds(
        (const __attribute__((address_space(1))) void*)g,
        (__attribute__((address_space(3))) void*)l,
        16, 0, 0);
}

// Inline-asm ds_read_b128: invisible to the compiler's LDS-DMA waitcnt
// tracking, so no hidden `s_waitcnt vmcnt(0)` gets inserted before the
// fragment reads (the counted-vmcnt pipeline stays live across phases).
// Completion is enforced by our explicit lgkmcnt(0) + sched_barrier(0).
__device__ __forceinline__ mfma_in ds_read128(const u16* p) {
    i32x4 r;
    unsigned off = (unsigned)(size_t)(const __attribute__((address_space(3))) u16*)p;
    asm volatile("ds_read_b128 %0, %1" : "=v"(r) : "v"(off));
    return __builtin_bit_cast(mfma_in, r);
}

// ---------------------------------------------------------------- conversions
#define XF4 (MM * DM / 4)
#define WF4 (DM * DM / 4)
__global__ __launch_bounds__(256)
void cvt_all(const float* __restrict__ x,
             const float* __restrict__ w0, const float* __restrict__ w1,
             const float* __restrict__ w2, const float* __restrict__ w3,
             u16* __restrict__ dst) {
    int i = blockIdx.x * 256 + threadIdx.x;
    const float* src;
    int si;
    if (i < XF4) { src = x; si = i; }
    else {
        int j = i - XF4;
        const float* ws[4] = {w0, w1, w2, w3};
        src = ws[j >> 18];
        si = j & (WF4 - 1);
    }
    float4 f = ((const float4*)src)[si];
    ushort4 o;
    o.x = f2bf(f.x); o.y = f2bf(f.y); o.z = f2bf(f.z); o.w = f2bf(f.w);
    ((ushort4*)dst)[i] = o;
}

// ---------------------------------------------------------------- 256^2 8-phase GEMM
// LDS layout per 256x64 K-tile buffer: row = 64 u16 (8 chunks of 16B),
// chunk at (row, logical c) stored at phys = c ^ (row&7) (XOR bank swizzle).
// Staging: swizzle pre-folded into the GLOBAL source address (linear LDS dest).
// Fragment read: row r, k-step s, logical chunk 4s+quad -> phys (4s+quad)^(r&7).
//
// 8-phase schedule per iteration (2 K-tiles k=2it -> buf0, k+1 -> buf1):
//   ph1 Q0(i0-3,j0-1)@buf0: ld aL,bL | stage B-h0(k+1)->buf1
//   ph2 Q1(i4-7,j0-1)@buf0: ld aH    | stage B-h1(k+1)->buf1
//   ph3 Q2(i0-3,j2-3)@buf0: ld bH    | stage A-h0(k+2)->buf0   (A slots last read ph2)
//   ph4 Q3(i4-7,j2-3)@buf0:          | stage A-h1(k+2)->buf0 | vmcnt(4)
//   ph5..ph8: same on buf1; stages B(k+2)->buf0, A(k+3)->buf1 | vmcnt(4)
// vmcnt(4) leaves only the 2 newest half-tiles in flight. Stage K-index wraps
// &15 at the tail: garbage lands only in slots whose last read already happened.

template<int IOFF, int JOFF>
__device__ __forceinline__ void mfmaQ(const mfma_in (&a)[4][2], const mfma_in (&b)[2][2],
                                      f32x4 (&acc)[8][4]) {
#pragma unroll
    for (int s = 0; s < 2; s++)
#pragma unroll
        for (int i = 0; i < 4; i++)
#pragma unroll
            for (int j = 0; j < 2; j++)
                acc[IOFF + i][JOFF + j] = __builtin_amdgcn_mfma_f32_16x16x32_bf16(
                    a[i][s], b[j][s], acc[IOFF + i][JOFF + j], 0, 0, 0);
}

// NOTE: no "memory" clobbers on the waitcnt asms — a clobber makes the asm a
// may-load/may-store op and the waitcnt pass then drains outstanding LDS-DMA
// (vmcnt(0)) in front of it, killing the counted-vmcnt pipeline.
#define PH_MID() do { \
    __builtin_amdgcn_s_barrier(); \
    asm volatile("s_waitcnt lgkmcnt(0)"); \
    __builtin_amdgcn_sched_barrier(0); \
    __builtin_amdgcn_s_setprio(1); \
} while (0)

#define PH_END() do { \
    __builtin_amdgcn_s_setprio(0); \
    __builtin_amdgcn_sched_barrier(0); \
    __builtin_amdgcn_s_barrier(); \
} while (0)

#define PH_END_VM() do { \
    __builtin_amdgcn_s_setprio(0); \
    __builtin_amdgcn_sched_barrier(0); \
    asm volatile("s_waitcnt vmcnt(4)"); \
    __builtin_amdgcn_s_barrier(); \
} while (0)

__device__ __forceinline__ void mainloop256(
    const u16* __restrict__ A, const u16* __restrict__ B,
    int mBlk, int nBlk,
    u16 (*__restrict__ As)[256 * 64], u16 (*__restrict__ Bs)[256 * 64],
    f32x4 (&acc)[8][4]) {
    const int tid  = threadIdx.x;
    const int wave = tid >> 6;
    const int lane = tid & 63;
    const int quad = lane >> 4;
    const int l16  = lane & 15;
    const int wm   = (wave >> 2) * 128;   // wave-row: 0..1 -> A half
    const int wn   = (wave & 3) * 64;     // wave-col: 0..3

    // staging addressing (swizzle folded into global source)
    const int sRow = wave * 8 + (lane >> 3);
    const int sCol = ((lane & 7) ^ (lane >> 3)) * 8;
    const u16* gA = A + (size_t)(mBlk + sRow) * DM + sCol;
    const u16* gB = B + (size_t)(nBlk + sRow) * DM + sCol;
    const int ldsW = wave * 8 * 64;       // wave's element offset within a 64-row segment

    // fragment read offsets
    int rA[8], rB[4];
#pragma unroll
    for (int i = 0; i < 8; i++) rA[i] = (wm + i * 16 + l16) * 64;
#pragma unroll
    for (int j = 0; j < 4; j++) rB[j] = (wn + j * 16 + l16) * 64;
    const int c0 = ((quad    ) ^ (l16 & 7)) * 8;
    const int c1 = ((quad + 4) ^ (l16 & 7)) * 8;

#define STG_A(buf, h, t) do { \
    const int kk_ = ((t) & (NKT - 1)) * BKT; \
    gld_lds16(gA + (size_t)((h) * 128) * DM + kk_,      &As[buf][((h) * 128) * 64 + ldsW]); \
    gld_lds16(gA + (size_t)((h) * 128 + 64) * DM + kk_, &As[buf][((h) * 128 + 64) * 64 + ldsW]); \
} while (0)
#define STG_B(buf, h, t) do { \
    const int kk_ = ((t) & (NKT - 1)) * BKT; \
    gld_lds16(gB + (size_t)((h) * 128) * DM + kk_,      &Bs[buf][((h) * 128) * 64 + ldsW]); \
    gld_lds16(gB + (size_t)((h) * 128 + 64) * DM + kk_, &Bs[buf][((h) * 128 + 64) * 64 + ldsW]); \
} while (0)
#define LDA(dst, buf, i, s) (dst) = ds_read128(&As[buf][rA[i] + ((s) ? c1 : c0)])
#define LDB(dst, buf, j, s) (dst) = ds_read128(&Bs[buf][rB[j] + ((s) ? c1 : c0)])

    mfma_in aL[4][2], aH[4][2], bL[2][2], bH[2][2];

    // prologue: tile 0 complete + A halves of tile 1 (B(1) staged in ph1/ph2)
    STG_A(0, 0, 0); STG_A(0, 1, 0);
    STG_B(0, 0, 0); STG_B(0, 1, 0);
    STG_A(1, 0, 1); STG_A(1, 1, 1);
    asm volatile("s_waitcnt vmcnt(4)");   // tile 0's 8 loads landed
    __builtin_amdgcn_s_barrier();

#pragma unroll 1
    for (int it = 0; it < NKT / 2; ++it) {
        const int k = 2 * it;

        // ---- tile k (buf0) ----
        // ph1: Q0
#pragma unroll
        for (int i = 0; i < 4; i++) { LDA(aL[i][0], 0, i, 0); LDA(aL[i][1], 0, i, 1); }
#pragma unroll
        for (int j = 0; j < 2; j++) { LDB(bL[j][0], 0, j, 0); LDB(bL[j][1], 0, j, 1); }
        STG_B(1, 0, k + 1);
        PH_MID();
        mfmaQ<0, 0>(aL, bL, acc);
        PH_END();

        // ph2: Q1
#pragma unroll
        for (int i = 0; i < 4; i++) { LDA(aH[i][0], 0, i + 4, 0); LDA(aH[i][1], 0, i + 4, 1); }
        STG_B(1, 1, k + 1);
        PH_MID();
        mfmaQ<4, 0>(aH, bL, acc);
        PH_END();

        // ph3: Q2
#pragma unroll
        for (int j = 0; j < 2; j++) { LDB(bH[j][0], 0, j + 2, 0); LDB(bH[j][1], 0, j + 2, 1); }
        STG_A(0, 0, k + 2);
        PH_MID();
        mfmaQ<0, 2>(aL, bH, acc);
        PH_END();

        // ph4: Q3
        STG_A(0, 1, k + 2);
        PH_MID();
        mfmaQ<4, 2>(aH, bH, acc);
        PH_END_VM();   // vmcnt(4): only A(k+2) halves in flight; tile k+1 landed

        // ---- tile k+1 (buf1) ----
        // ph5: Q0
#pragma unroll
        for (int i = 0; i < 4; i++) { LDA(aL[i][0], 1, i, 0); LDA(aL[i][1], 1, i, 1); }
#pragma unroll
        for (int j = 0; j < 2; j++) { LDB(bL[j][0], 1, j, 0); LDB(bL[j][1], 1, j, 1); }
        STG_B(0, 0, k + 2);
        PH_MID();
        mfmaQ<0, 0>(aL, bL, acc);
        PH_END();

        // ph6: Q1
#pragma unroll
        for (int i = 0; i < 4; i++) { LDA(aH[i][0], 1, i + 4, 0); LDA(aH[i][1], 1, i + 4, 1); }
        STG_B(0, 1, k + 2);
        PH_MID();
        mfmaQ<4, 0>(aH, bL, acc);
        PH_END();

        // ph7: Q2
#pragma unroll
        for (int j = 0; j < 2; j++) { LDB(bH[j][0], 1, j + 2, 0); LDB(bH[j][1], 1, j + 2, 1); }
        STG_A(1, 0, k + 3);
        PH_MID();
        mfmaQ<0, 2>(aL, bH, acc);
        PH_END();

        // ph8: Q3
        STG_A(1, 1, k + 3);
        PH_MID();
        mfmaQ<4, 2>(aH, bH, acc);
        PH_END_VM();   // vmcnt(4): only A(k+3) halves in flight; tile k+2 landed
    }
#undef STG_A
#undef STG_B
#undef LDA
#undef LDB
}

// fused q/v/g projection: B = concatenated 3072x1024 weights; 3 bf16 outputs
__global__ __launch_bounds__(512, 2)
void gemm_qvg(const u16* __restrict__ A, const u16* __restrict__ B,
              u16* __restrict__ oq, u16* __restrict__ ov, u16* __restrict__ og) {
    __shared__ __align__(16) u16 As[2][256 * 64];
    __shared__ __align__(16) u16 Bs[2][256 * 64];
    const int mBlk = blockIdx.x * 256;
    const int nBlk = blockIdx.y * 256;

    f32x4 acc[8][4] = {};
    mainloop256(A, B, mBlk, nBlk, As, Bs, acc);

    const int tid  = threadIdx.x;
    const int wave = tid >> 6;
    const int lane = tid & 63;
    const int quad = lane >> 4;
    const int l16  = lane & 15;
    const int wm   = (wave >> 2) * 128;
    const int wn   = (wave & 3) * 64;

    u16* outs[3] = {oq, ov, og};
    u16* O = outs[nBlk >> 10];
    const int nIn = nBlk & 1023;
#pragma unroll
    for (int i = 0; i < 8; i++) {
        int row0 = mBlk + wm + i * 16 + quad * 4;
#pragma unroll
        for (int j = 0; j < 4; j++) {
            int col = nIn + wn + j * 16 + l16;
#pragma unroll
            for (int r = 0; r < 4; r++)
                O[(size_t)(row0 + r) * DM + col] = f2bf(acc[i][j][r]);
        }
    }
}

// output projection: C (f32) = A @ B^T
__global__ __launch_bounds__(512, 2)
void gemm_out(const u16* __restrict__ A, const u16* __restrict__ B,
              float* __restrict__ C) {
    __shared__ __align__(16) u16 As[2][256 * 64];
    __shared__ __align__(16) u16 Bs[2][256 * 64];
    const int mBlk = blockIdx.x * 256;
    const int nBlk = blockIdx.y * 256;

    f32x4 acc[8][4] = {};
    mainloop256(A, B, mBlk, nBlk, As, Bs, acc);

    const int tid  = threadIdx.x;
    const int wave = tid >> 6;
    const int lane = tid & 63;
    const int quad = lane >> 4;
    const int l16  = lane & 15;
    const int wm   = (wave >> 2) * 128;
    const int wn   = (wave & 3) * 64;

#pragma unroll
    for (int i = 0; i < 8; i++) {
        int row0 = mBlk + wm + i * 16 + quad * 4;
#pragma unroll
        for (int j = 0; j < 4; j++) {
            int col = nBlk + wn + j * 16 + l16;
#pragma unroll
            for (int r = 0; r < 4; r++)
                C[(size_t)(row0 + r) * DM + col] = acc[i][j][r];
        }
    }
}

// ---------------------------------------------------------------- scan phase A
__global__ __launch_bounds__(256)
void scan_ends(const u16* __restrict__ v, const float* __restrict__ beta,
               float* __restrict__ ebuf) {
    int d = blockIdx.x * 256 + threadIdx.x;
    int c = blockIdx.y, b = blockIdx.z;
    int h = d >> 6;
    float lam = 1.0f / (1.0f + __expf(-beta[h]));
    size_t idx = ((size_t)b * LL + (size_t)c * LC2) * DM + d;
    float s = 0.0f;
#pragma unroll
    for (int i = 0; i < LC2; i++) {
        s = lam * s + bf2f(v[idx]);
        idx += DM;
    }
    ebuf[((size_t)b * CC2 + c) * DM + d] = s;
}

// ---------------------------------------------------------------- scan phase B
__global__ __launch_bounds__(256)
void scan_carry(const float* __restrict__ ebuf, const float* __restrict__ beta,
                float* __restrict__ carry) {
    int ch = blockIdx.x * 256 + threadIdx.x;  // 0..BB*DM-1
    int b = ch >> 10, d = ch & 1023;
    int h = d >> 6;
    float lam = 1.0f / (1.0f + __expf(-beta[h]));
    float lamC = lam;
    for (int i = 0; i < 4; i++) lamC *= lamC;  // lam^16
    float cur = 0.0f;
#pragma unroll 8
    for (int c = 0; c < CC2; c++) {
        size_t idx = ((size_t)b * CC2 + c) * DM + d;
        carry[idx] = cur;
        cur = lamC * cur + ebuf[idx];
    }
}

// ---------------------------------------------------------------- scan phase C:
// seeded re-scan + y=q*state + LayerNorm + SiLU gate -> bf16
__global__ __launch_bounds__(256)
void scan_ln_gate(const u16* __restrict__ v, const u16* __restrict__ q,
                  const u16* __restrict__ g, const float* __restrict__ carry,
                  const float* __restrict__ beta, const float* __restrict__ gamma,
                  const float* __restrict__ lnb, u16* __restrict__ out) {
    __shared__ float red[2][8];
    const int t = threadIdx.x;
    const int c = blockIdx.x, b = blockIdx.y;
    const int wave = t >> 6, lane = t & 63;
    const int d0 = t * 4;
    const int h = d0 >> 6;
    float lam = 1.0f / (1.0f + __expf(-beta[h]));
    float4 gm = ((const float4*)gamma)[t];
    float4 bt = ((const float4*)lnb)[t];
    float4 cr = *(const float4*)(carry + ((size_t)b * CC2 + c) * DM + d0);
    float s0 = cr.x, s1 = cr.y, s2 = cr.z, s3 = cr.w;
    size_t base = ((size_t)b * LL + (size_t)c * LC2) * DM + d0;

    for (int i = 0; i < LC2; i++) {
        ushort4 v4 = *(const ushort4*)(v + base);
        ushort4 q4 = *(const ushort4*)(q + base);
        ushort4 g4 = *(const ushort4*)(g + base);
        s0 = lam * s0 + bf2f(v4.x);
        s1 = lam * s1 + bf2f(v4.y);
        s2 = lam * s2 + bf2f(v4.z);
        s3 = lam * s3 + bf2f(v4.w);
        float y0 = bf2f(q4.x) * s0, y1 = bf2f(q4.y) * s1;
        float y2 = bf2f(q4.z) * s2, y3 = bf2f(q4.w) * s3;
        float sum = y0 + y1 + y2 + y3;
        float sq  = y0 * y0 + y1 * y1 + y2 * y2 + y3 * y3;
#pragma unroll
        for (int off = 32; off > 0; off >>= 1) {
            sum += __shfl_xor(sum, off);
            sq  += __shfl_xor(sq, off);
        }
        int p = i & 1;
        if (lane == 0) { red[p][wave] = sum; red[p][4 + wave] = sq; }
        __syncthreads();
        float ts = red[p][0] + red[p][1] + red[p][2] + red[p][3];
        float tq = red[p][4] + red[p][5] + red[p][6] + red[p][7];
        float mu  = ts * (1.0f / DM);
        float inv = rsqrtf(tq * (1.0f / DM) - mu * mu + 1e-5f);

        float gv0 = bf2f(g4.x), gv1 = bf2f(g4.y), gv2 = bf2f(g4.z), gv3 = bf2f(g4.w);
        float x0 = ((y0 - mu) * inv * gm.x + bt.x) * (gv0 / (1.0f + __expf(-gv0)));
        float x1 = ((y1 - mu) * inv * gm.y + bt.y) * (gv1 / (1.0f + __expf(-gv1)));
        float x2 = ((y2 - mu) * inv * gm.z + bt.z) * (gv2 / (1.0f + __expf(-gv2)));
        float x3 = ((y3 - mu) * inv * gm.w + bt.w) * (gv3 / (1.0f + __expf(-gv3)));
        ushort4 o;
        o.x = f2bf(x0); o.y = f2bf(x1); o.z = f2bf(x2); o.w = f2bf(x3);
        *(ushort4*)(out + base) = o;
        base += DM;
    }
}

// ---------------------------------------------------------------- launcher
extern "C" void kernel_launch(void* const* d_in, const int* in_sizes, int n_in,
                              void* d_out, int out_size, void* d_ws, size_t ws_size,
                              hipStream_t stream) {
    const float* x     = (const float*)d_in[0];
    const float* Wq    = (const float*)d_in[1];
    const float* Wv    = (const float*)d_in[2];
    const float* Wg    = (const float*)d_in[3];
    const float* Wo    = (const float*)d_in[4];
    const float* beta  = (const float*)d_in[5];
    const float* gamma = (const float*)d_in[6];
    const float* lnb   = (const float*)d_in[7];

    // workspace layout (bf16 elements) — xb..Wob contiguous for cvt_all
    u16* xb  = (u16*)d_ws;                    // reused as y_final
    u16* Wqb = xb + (size_t)MM * DM;          // Wq,Wv,Wg concat = 3072x1024
    u16* Wob = Wqb + (size_t)3 * DM * DM;
    u16* qb  = Wob + (size_t)DM * DM;
    u16* vb  = qb + (size_t)MM * DM;
    u16* gb  = vb + (size_t)MM * DM;
    float* ebuf  = (float*)(gb + (size_t)MM * DM);   // BB*CC2*DM f32
    float* carry = ebuf + (size_t)BB * CC2 * DM;
    u16* yfin = xb;

    // 1) fp32 -> bf16, single launch
    cvt_all<<<(XF4 + 4 * WF4 + 255) / 256, 256, 0, stream>>>(x, Wq, Wv, Wg, Wo, xb);

    // 2) fused q/v/g projection (N=3072 concat), 256x256 8-phase
    dim3 gq(MM / 256, 3 * DM / 256);
    gemm_qvg<<<gq, 512, 0, stream>>>(xb, Wqb, qb, vb, gb);

    // 3) retention scan (chunked) + fused LN + SiLU gate
    dim3 gs(DM / 256, CC2, BB);
    scan_ends<<<gs, 256, 0, stream>>>(vb, beta, ebuf);
    scan_carry<<<(BB * DM) / 256, 256, 0, stream>>>(ebuf, beta, carry);
    dim3 gf(CC2, BB);
    scan_ln_gate<<<gf, 256, 0, stream>>>(vb, qb, gb, carry, beta, gamma, lnb, yfin);

    // 4) output projection (fp32 out), 256x256 8-phase
    dim3 go(MM / 256, DM / 256);
    gemm_out<<<go, 512, 0, stream>>>(yfin, Wob, (float*)d_out);
}